// Round 2
// baseline (17893.613 us; speedup 1.0000x reference)
//
#include <hip/hip_runtime.h>

// Persistent batched-GRU kernel for MI355X (gfx950), round 2.
// B=16384, T=1024, H=256. 256 blocks x 1024 threads (16 waves, 1 block/CU).
// Each block owns 64 batch rows for all 1024 steps; each wave owns 16 matched
// gate columns (c, c+256, c+512) so r,z,n align in its own accumulators.
// Round-2 changes vs round 1:
//  - 16 waves x 16 cols (was 8 x 32): per-lane acc 48+16 regs -> no spill,
//    occupancy 8 -> 16 waves/CU (4/SIMD) for vmem latency hiding.
//  - x and out staged through LDS in 64-step chunks with coalesced float4
//    refill/flush (was per-step 4B @ 4KB-stride global accesses).

#define B_TOTAL 16384
#define T_LEN   1024
#define M_ROWS  64                      // batch rows per block
#define NBLOCKS (B_TOTAL / M_ROWS)      // 256 -> 1 block/CU
#define NTHREADS 1024                   // 16 waves
#define LDSW    264                     // h row stride in bf16 (pad 256+8)
#define TCH     64                      // t-chunk length
#define XSTR    68                      // x_buf/out_buf row stride in floats

typedef short  short8 __attribute__((ext_vector_type(8)));
typedef float  f32x4  __attribute__((ext_vector_type(4)));

__device__ __forceinline__ unsigned short f2b(float f) {
  unsigned u = __builtin_bit_cast(unsigned, f);
  u += 0x7fffu + ((u >> 16) & 1u);
  return (unsigned short)(u >> 16);
}
__device__ __forceinline__ float fast_sig(float x) {
  return 1.0f / (1.0f + __expf(-x));
}
__device__ __forceinline__ float fast_tanh(float x) {
  return 2.0f * fast_sig(2.0f * x) - 1.0f;
}

// Swizzle W_hh (768x256 f32 row-major) into fragment-major bf16:
// dst[((nt*8 + ks)*64 + lane)*8 + e] = bf16(W[nt*16 + (lane&15)][ks*32 + (lane>>4)*8 + e])
__global__ void prep_w(const float* __restrict__ w_hh, unsigned short* __restrict__ wsw) {
  int tid  = blockIdx.x * 256 + threadIdx.x;     // 196608 total
  int e    = tid & 7;
  int lane = (tid >> 3) & 63;
  int ks   = (tid >> 9) & 7;
  int nt   = tid >> 12;
  int row  = nt * 16 + (lane & 15);
  int col  = ks * 32 + (lane >> 4) * 8 + e;
  wsw[tid] = f2b(w_hh[row * 256 + col]);
}

__global__ __launch_bounds__(NTHREADS, 4) void gru_kernel(
    const float* __restrict__ x,
    const float* __restrict__ w_ih,
    const float* __restrict__ b_ih,
    const float* __restrict__ b_hh,
    const float* __restrict__ w_out,
    const float* __restrict__ b_out,
    const unsigned short* __restrict__ wsw,
    float* __restrict__ out)
{
  __shared__ unsigned short h_lds[M_ROWS * LDSW];   // ~33 KB, A-operand source
  __shared__ float x_buf[M_ROWS * XSTR];            // 17 KB, 64-step x chunk
  __shared__ float out_buf[M_ROWS * XSTR];          // 17 KB, 64-step out chunk
  __shared__ float out_part[16][M_ROWS];            // 4 KB

  const int tid  = threadIdx.x;
  const int w    = tid >> 6;        // wave 0..15
  const int lane = tid & 63;
  const int r16  = lane & 15;
  const int q    = lane >> 4;
  const long base = (long)blockIdx.x * M_ROWS;

  for (int i = tid; i < M_ROWS * LDSW; i += NTHREADS) h_lds[i] = 0;  // h0 = 0

  // this wave's matched column: c, c+256, c+512
  const int c = w * 16 + r16;
  const float wi_r  = w_ih[c];
  const float wi_z  = w_ih[256 + c];
  const float wi_n  = w_ih[512 + c];
  const float bt_r  = b_ih[c]       + b_hh[c];
  const float bt_z  = b_ih[256 + c] + b_hh[256 + c];
  const float bih_n = b_ih[512 + c];
  const float bhh_n = b_hh[512 + c];
  const float wo    = w_out[c];
  const float bo    = b_out[0];
  const f32x4 zero4 = {0.f, 0.f, 0.f, 0.f};

  f32x4 h_reg[4];                   // C layout: row = mt*16 + q*4 + i, col = c
#pragma unroll
  for (int mt = 0; mt < 4; ++mt) h_reg[mt] = zero4;

  // B-frag base: frag (g, ks) at ((g*16 + w)*8 + ks)*512 + lane*8 elements
  const unsigned short* bp[3];
#pragma unroll
  for (int g = 0; g < 3; ++g)
    bp[g] = wsw + ((long)((g * 16 + w) * 8) * 64 + lane) * 8;

  const int row64 = tid >> 4;            // 0..63 (chunk refill/flush role)
  const int ko    = (tid & 15) * 4;

  for (int tc = 0; tc < T_LEN / TCH; ++tc) {
    // ---- refill x chunk (coalesced float4)
    {
      const float4 v = *(const float4*)&x[(base + row64) * T_LEN + tc * TCH + ko];
      *(float4*)&x_buf[row64 * XSTR + ko] = v;
    }
    __syncthreads();   // x_buf ready (also covers h_lds init on tc==0)

    for (int tr = 0; tr < TCH; ++tr) {
      // ---------- Phase A: gh = h @ W_hh^T (4 m-tiles x 3 gates x 8 k-steps)
      f32x4 acc[4][3];
#pragma unroll
      for (int mt = 0; mt < 4; ++mt)
#pragma unroll
        for (int g = 0; g < 3; ++g) acc[mt][g] = zero4;

#pragma unroll
      for (int ks = 0; ks < 8; ++ks) {
        short8 a[4];
#pragma unroll
        for (int mt = 0; mt < 4; ++mt)
          a[mt] = *(const short8*)&h_lds[(mt * 16 + r16) * LDSW + ks * 32 + q * 8];
#pragma unroll
        for (int g = 0; g < 3; ++g) {
          short8 b = *(const short8*)(bp[g] + ks * 512);
#pragma unroll
          for (int mt = 0; mt < 4; ++mt)
            acc[mt][g] = __builtin_amdgcn_mfma_f32_16x16x32_bf16(a[mt], b, acc[mt][g], 0, 0, 0);
        }
      }

      // ---------- Phase B: gates in-register
      f32x4 vout[4];
#pragma unroll
      for (int mt = 0; mt < 4; ++mt) {
        f32x4 xv;
#pragma unroll
        for (int i = 0; i < 4; ++i) xv[i] = x_buf[(mt * 16 + q * 4 + i) * XSTR + tr];
#pragma unroll
        for (int i = 0; i < 4; ++i) {
          float rg = fast_sig(acc[mt][0][i] + xv[i] * wi_r + bt_r);
          float zg = fast_sig(acc[mt][1][i] + xv[i] * wi_z + bt_z);
          float ng = fast_tanh(xv[i] * wi_n + bih_n + rg * (acc[mt][2][i] + bhh_n));
          float hn = (1.0f - zg) * ng + zg * h_reg[mt][i];
          h_reg[mt][i] = hn;
          vout[mt][i] = fmaxf(hn, 0.0f) * wo;
        }
#pragma unroll
        for (int mask = 1; mask < 16; mask <<= 1)
#pragma unroll
          for (int i = 0; i < 4; ++i)
            vout[mt][i] += __shfl_xor(vout[mt][i], mask, 16);
      }

      __syncthreads();   // barrier1: A-frag + x_buf reads + prev Phase D done

      // ---------- Phase C: publish h_new (bf16) + out partials
#pragma unroll
      for (int mt = 0; mt < 4; ++mt)
#pragma unroll
        for (int i = 0; i < 4; ++i)
          h_lds[(mt * 16 + q * 4 + i) * LDSW + c] = f2b(h_reg[mt][i]);
      if (r16 == 0) {
#pragma unroll
        for (int mt = 0; mt < 4; ++mt)
#pragma unroll
          for (int i = 0; i < 4; ++i)
            out_part[w][mt * 16 + q * 4 + i] = vout[mt][i];
      }

      __syncthreads();   // barrier2: h_lds / out_part ready

      // ---------- Phase D: per-step output into the chunk buffer
      if (tid < M_ROWS) {
        float o = bo;
#pragma unroll
        for (int ww = 0; ww < 16; ++ww) o += out_part[ww][tid];
        out_buf[tid * XSTR + tr] = o;
      }
    }

    __syncthreads();   // out_buf complete for this chunk
    // ---- flush out chunk (coalesced float4)
    {
      const float4 v = *(const float4*)&out_buf[row64 * XSTR + ko];
      *(float4*)&out[(base + row64) * T_LEN + tc * TCH + ko] = v;
    }
    // no barrier needed: next refill writes x_buf (disjoint), and out_buf is
    // next written in Phase D after that refill's __syncthreads.
  }
}

extern "C" void kernel_launch(void* const* d_in, const int* in_sizes, int n_in,
                              void* d_out, int out_size, void* d_ws, size_t ws_size,
                              hipStream_t stream) {
  const float* x     = (const float*)d_in[0];
  const float* w_ih  = (const float*)d_in[1];
  const float* w_hh  = (const float*)d_in[2];
  const float* b_ih  = (const float*)d_in[3];
  const float* b_hh  = (const float*)d_in[4];
  const float* w_out = (const float*)d_in[5];
  const float* b_out = (const float*)d_in[6];
  unsigned short* wsw = (unsigned short*)d_ws;   // 768*256*2 = 384 KB scratch
  float* out = (float*)d_out;

  prep_w<<<768, 256, 0, stream>>>(w_hh, wsw);
  gru_kernel<<<NBLOCKS, NTHREADS, 0, stream>>>(x, w_ih, b_ih, b_hh, w_out, b_out, wsw, out);
}

// Round 4
// 13371.069 us; speedup vs baseline: 1.3382x; 1.3382x over previous
//
#include <hip/hip_runtime.h>

// Persistent batched-GRU kernel for MI355X (gfx950), round 4.
// B=16384, T=1024, H=256. 256 blocks x 1024 threads (16 waves, 1 block/CU).
// Each block owns 64 batch rows for all 1024 steps; wave w owns matched gate
// columns c=w*16+r16 (+256,+512) so r,z,n align in its own accumulators.
// Round-4 change vs round 3 (which failed correctness):
//  - DPP row_shr reduction converges to the HIGHEST lane of each 16-lane row
//    (lane i reads lane i-N; LLVM's reduction idiom ends in the last lane).
//    Round 3 read the result from r16==0 -> out projection kept only 1 of 16
//    columns (absmax 3.4e-2). Fix: publish from r16==15.
// Carried from round 3:
//  - double-buffered h_lds + out_part -> ONE barrier per step
//  - v_rcp_f32 sigmoid (no div_scale/fmas/fixup sequences)
//  - DPP reduction on VALU pipe (no ds_bpermute on the loaded LDS pipe)
//  - x_buf transposed [t][row]: 4 broadcast ds_read_b128 per step
//  - b-frag global loads software-pipelined one k-step ahead

#define B_TOTAL 16384
#define T_LEN   1024
#define M_ROWS  64
#define NBLOCKS (B_TOTAL / M_ROWS)      // 256 -> 1 block/CU
#define NTHREADS 1024                   // 16 waves
#define LDSW    264                     // h row stride in shorts (16B-aligned rows)
#define TCH     32                      // t-chunk length
#define NCH     (T_LEN / TCH)
#define XSTR    68                      // x_buf t-row stride (floats): 272B, 16B-aligned
#define OSTR    37                      // out_buf row stride (floats): odd -> 2-way banks

typedef short short8 __attribute__((ext_vector_type(8)));
typedef float f32x4  __attribute__((ext_vector_type(4)));

__device__ __forceinline__ unsigned short f2b(float f) {
  unsigned u = __builtin_bit_cast(unsigned, f);
  u += 0x7fffu + ((u >> 16) & 1u);
  return (unsigned short)(u >> 16);
}
__device__ __forceinline__ float fast_sig(float x) {
  return __builtin_amdgcn_rcpf(1.0f + __expf(-x));   // v_exp + v_rcp, no div seq
}
__device__ __forceinline__ float fast_tanh(float x) {
  return 2.0f * fast_sig(2.0f * x) - 1.0f;
}
// sum over a 16-lane DPP row; result valid in the LAST lane of the row (r16==15)
__device__ __forceinline__ float dpp_red16(float v) {
  int x = __builtin_bit_cast(int, v);
  v += __builtin_bit_cast(float, __builtin_amdgcn_update_dpp(0, x, 0x118, 0xF, 0xF, true)); // row_shr:8
  x = __builtin_bit_cast(int, v);
  v += __builtin_bit_cast(float, __builtin_amdgcn_update_dpp(0, x, 0x114, 0xF, 0xF, true)); // row_shr:4
  x = __builtin_bit_cast(int, v);
  v += __builtin_bit_cast(float, __builtin_amdgcn_update_dpp(0, x, 0x112, 0xF, 0xF, true)); // row_shr:2
  x = __builtin_bit_cast(int, v);
  v += __builtin_bit_cast(float, __builtin_amdgcn_update_dpp(0, x, 0x111, 0xF, 0xF, true)); // row_shr:1
  return v;
}

// Swizzle W_hh (768x256 f32 row-major) into fragment-major bf16:
// dst[((nt*8 + ks)*64 + lane)*8 + e] = bf16(W[nt*16 + (lane&15)][ks*32 + (lane>>4)*8 + e])
__global__ void prep_w(const float* __restrict__ w_hh, unsigned short* __restrict__ wsw) {
  int tid  = blockIdx.x * 256 + threadIdx.x;     // 196608 total
  int e    = tid & 7;
  int lane = (tid >> 3) & 63;
  int ks   = (tid >> 9) & 7;
  int nt   = tid >> 12;
  int row  = nt * 16 + (lane & 15);
  int col  = ks * 32 + (lane >> 4) * 8 + e;
  wsw[tid] = f2b(w_hh[row * 256 + col]);
}

__global__ __launch_bounds__(NTHREADS, 4) void gru_kernel(
    const float* __restrict__ x,
    const float* __restrict__ w_ih,
    const float* __restrict__ b_ih,
    const float* __restrict__ b_hh,
    const float* __restrict__ w_out,
    const float* __restrict__ b_out,
    const unsigned short* __restrict__ wsw,
    float* __restrict__ out)
{
  __shared__ unsigned short h_lds[2][M_ROWS * LDSW];   // 2 x 33 KB (double-buffered h)
  __shared__ float x_buf[2][TCH * XSTR];               // 2 x 8.5 KB, [t][row]
  __shared__ float out_buf[2][M_ROWS * OSTR];          // 2 x 9.3 KB, [row][t]
  __shared__ float out_part[2][16][M_ROWS];            // 2 x 4 KB

  const int tid  = threadIdx.x;
  const int w    = tid >> 6;        // wave 0..15
  const int lane = tid & 63;
  const int r16  = lane & 15;
  const int q    = lane >> 4;
  const long base = (long)blockIdx.x * M_ROWS;

  for (int i = tid; i < M_ROWS * LDSW; i += NTHREADS) h_lds[0][i] = 0;  // h0 = 0

  const int c = w * 16 + r16;       // this wave's matched column
  const float wi_r  = w_ih[c];
  const float wi_z  = w_ih[256 + c];
  const float wi_n  = w_ih[512 + c];
  const float bt_r  = b_ih[c]       + b_hh[c];
  const float bt_z  = b_ih[256 + c] + b_hh[256 + c];
  const float bih_n = b_ih[512 + c];
  const float bhh_n = b_hh[512 + c];
  const float wo    = w_out[c];
  const float bo    = b_out[0];
  const f32x4 zero4 = {0.f, 0.f, 0.f, 0.f};

  f32x4 h_reg[4];                   // C layout: row = mt*16 + q*4 + i, col = c
#pragma unroll
  for (int mt = 0; mt < 4; ++mt) h_reg[mt] = zero4;

  // B-frag base: frag (g, ks) at ((g*16 + w)*8 + ks)*512 + lane*8 elements
  const unsigned short* bp[3];
#pragma unroll
  for (int g = 0; g < 3; ++g)
    bp[g] = wsw + ((long)((g * 16 + w) * 8) * 64 + lane) * 8;

  const int row64 = tid >> 4;            // 0..63 (refill/flush role)
  const int ko2   = (tid & 15) * 2;      // t-pair within chunk

  // prefill x chunk 0 (transposed into x_buf[0])
  {
    float2 v = *(const float2*)&x[(base + row64) * T_LEN + ko2];
    x_buf[0][(ko2 + 0) * XSTR + row64] = v.x;
    x_buf[0][(ko2 + 1) * XSTR + row64] = v.y;
  }
  __syncthreads();

  // one GRU step: reads h_lds[rp], x_buf[xp]; writes h_lds[rp^1], out_part[rp]
  auto gru_step = [&](int tr, int rp, int xp) {
    f32x4 acc[4][3];
#pragma unroll
    for (int mt = 0; mt < 4; ++mt)
#pragma unroll
      for (int g = 0; g < 3; ++g) acc[mt][g] = zero4;

    short8 bnx[3];
#pragma unroll
    for (int g = 0; g < 3; ++g) bnx[g] = *(const short8*)(bp[g]);
    const unsigned short* hb = &h_lds[rp][0];

#pragma unroll
    for (int ks = 0; ks < 8; ++ks) {
      short8 bc[3];
#pragma unroll
      for (int g = 0; g < 3; ++g) bc[g] = bnx[g];
      if (ks < 7) {
#pragma unroll
        for (int g = 0; g < 3; ++g)
          bnx[g] = *(const short8*)(bp[g] + (ks + 1) * 512);   // prefetch next k-step
      }
      short8 a[4];
#pragma unroll
      for (int mt = 0; mt < 4; ++mt)
        a[mt] = *(const short8*)&hb[(mt * 16 + r16) * LDSW + ks * 32 + q * 8];
#pragma unroll
      for (int g = 0; g < 3; ++g)
#pragma unroll
        for (int mt = 0; mt < 4; ++mt)
          acc[mt][g] = __builtin_amdgcn_mfma_f32_16x16x32_bf16(a[mt], bc[g], acc[mt][g], 0, 0, 0);
    }

    // gates + h publish + out partial, fused (writes to h_lds[rp^1] are safe
    // pre-barrier: all reads of that buffer finished before the previous barrier)
    unsigned short* hw = &h_lds[rp ^ 1][0];
#pragma unroll
    for (int mt = 0; mt < 4; ++mt) {
      f32x4 xv = *(const f32x4*)&x_buf[xp][tr * XSTR + mt * 16 + q * 4];  // broadcast b128
      f32x4 vo;
#pragma unroll
      for (int i = 0; i < 4; ++i) {
        float rg = fast_sig(acc[mt][0][i] + xv[i] * wi_r + bt_r);
        float zg = fast_sig(acc[mt][1][i] + xv[i] * wi_z + bt_z);
        float ng = fast_tanh(xv[i] * wi_n + bih_n + rg * (acc[mt][2][i] + bhh_n));
        float hn = (1.0f - zg) * ng + zg * h_reg[mt][i];
        h_reg[mt][i] = hn;
        hw[(mt * 16 + q * 4 + i) * LDSW + c] = f2b(hn);
        vo[i] = fmaxf(hn, 0.0f) * wo;
      }
#pragma unroll
      for (int i = 0; i < 4; ++i) vo[i] = dpp_red16(vo[i]);
      if (r16 == 15) {   // row_shr reduction converges into the LAST lane
#pragma unroll
        for (int i = 0; i < 4; ++i)
          out_part[rp][w][mt * 16 + q * 4 + i] = vo[i];
      }
    }
  };

#pragma unroll 1
  for (int tc = 0; tc < NCH; ++tc) {
    const int xp = tc & 1;
    const int ob = tc & 1;
#pragma unroll 1
    for (int tr = 0; tr < TCH; tr += 2) {
      // ---- even step (rp = 0)
      gru_step(tr, 0, xp);
      if (tr == 0 && tc + 1 < NCH) {    // refill next x chunk (disjoint buffer)
        float2 v = *(const float2*)&x[(base + row64) * T_LEN + (tc + 1) * TCH + ko2];
        x_buf[xp ^ 1][(ko2 + 0) * XSTR + row64] = v.x;
        x_buf[xp ^ 1][(ko2 + 1) * XSTR + row64] = v.y;
      }
      __syncthreads();
      if (tid < M_ROWS) {               // wave 0: finalize out for this step
        float o = bo;
#pragma unroll
        for (int ww = 0; ww < 16; ++ww) o += out_part[0][ww][tid];
        out_buf[ob][tid * OSTR + tr] = o;
      }
      if (tr == 0 && tc > 0) {          // flush previous chunk (coalesced float2)
        float2 v;
        v.x = out_buf[ob ^ 1][row64 * OSTR + ko2];
        v.y = out_buf[ob ^ 1][row64 * OSTR + ko2 + 1];
        *(float2*)&out[(base + row64) * T_LEN + (tc - 1) * TCH + ko2] = v;
      }
      // ---- odd step (rp = 1)
      gru_step(tr + 1, 1, xp);
      __syncthreads();
      if (tid < M_ROWS) {
        float o = bo;
#pragma unroll
        for (int ww = 0; ww < 16; ++ww) o += out_part[1][ww][tid];
        out_buf[ob][tid * OSTR + tr + 1] = o;
      }
    }
  }
  __syncthreads();
  {  // flush final chunk
    float2 v;
    v.x = out_buf[(NCH - 1) & 1][row64 * OSTR + ko2];
    v.y = out_buf[(NCH - 1) & 1][row64 * OSTR + ko2 + 1];
    *(float2*)&out[(base + row64) * T_LEN + (NCH - 1) * TCH + ko2] = v;
  }
}

extern "C" void kernel_launch(void* const* d_in, const int* in_sizes, int n_in,
                              void* d_out, int out_size, void* d_ws, size_t ws_size,
                              hipStream_t stream) {
  const float* x     = (const float*)d_in[0];
  const float* w_ih  = (const float*)d_in[1];
  const float* w_hh  = (const float*)d_in[2];
  const float* b_ih  = (const float*)d_in[3];
  const float* b_hh  = (const float*)d_in[4];
  const float* w_out = (const float*)d_in[5];
  const float* b_out = (const float*)d_in[6];
  unsigned short* wsw = (unsigned short*)d_ws;   // 768*256*2 = 384 KB scratch
  float* out = (float*)d_out;

  prep_w<<<768, 256, 0, stream>>>(w_hh, wsw);
  gru_kernel<<<NBLOCKS, NTHREADS, 0, stream>>>(x, w_ih, b_ih, b_hh, w_out, b_out, wsw, out);
}